// Round 2
// baseline (234.636 us; speedup 1.0000x reference)
//
#include <hip/hip_runtime.h>

#define N_PIX  131072       // 32*64*64 pixels
#define D      64
#define K      512
#define Q_OFF  0            // out[0 .. 8388607]   quantized_ste (NCHW), 32*64*64*64
#define L_OFF  8388608      // out[8388608]        commitment loss
#define I_OFF  8388609      // out[8388609 .. ]    indices (as float), 131072

// ws layout (floats)
#define WS_ET     0                 // 512*64 transposed embeddings
#define WS_ENORM  (K * D)           // 512 code norms
#define WS_PART   (K * D + K)       // 512 partial loss sums

__global__ __launch_bounds__(256) void vq_prep(const float* __restrict__ E,
                                               float* __restrict__ ws) {
    int k = blockIdx.x * 256 + threadIdx.x;   // 0..511
    float* ET = ws + WS_ET;
    float nsq = 0.f;
#pragma unroll 8
    for (int d = 0; d < D; ++d) {
        float v = E[d * K + k];               // coalesced across k
        ET[k * D + d] = v;
        nsq = fmaf(v, v, nsq);
    }
    ws[WS_ENORM + k] = nsq;
}

__global__ __launch_bounds__(256) void vq_main(const float* __restrict__ x,
                                               const float* __restrict__ ws,
                                               float* __restrict__ out,
                                               float* __restrict__ partial) {
    const float* ET    = ws + WS_ET;
    const float* enorm = ws + WS_ENORM;

    int n  = blockIdx.x * 256 + threadIdx.x;  // pixel id
    int b  = n >> 12;                         // n / 4096
    int hw = n & 4095;

    const float* xp = x + ((size_t)b << 18) + hw;   // b*64*4096 + hw
    float xv[D];
#pragma unroll
    for (int d = 0; d < D; ++d) xv[d] = xp[(size_t)d << 12];

    float best  = 3.4e38f;
    int   bestk = 0;
    for (int k = 0; k < K; ++k) {
        const float4* ek = reinterpret_cast<const float4*>(ET + (k << 6)); // uniform addr
        float a0 = 0.f, a1 = 0.f, a2 = 0.f, a3 = 0.f;
#pragma unroll
        for (int q = 0; q < 16; ++q) {
            float4 e = ek[q];
            a0 = fmaf(xv[4*q+0], e.x, a0);
            a1 = fmaf(xv[4*q+1], e.y, a1);
            a2 = fmaf(xv[4*q+2], e.z, a2);
            a3 = fmaf(xv[4*q+3], e.w, a3);
        }
        float dot  = (a0 + a1) + (a2 + a3);
        float dist = fmaf(-2.f, dot, enorm[k]);   // ||x||^2 omitted: constant per pixel
        if (dist < best) { best = dist; bestk = k; }   // strict < -> first min, like np.argmin
    }

    out[I_OFF + n] = (float)bestk;

    const float* qv = ET + (bestk << 6);
    float* op = out + Q_OFF + ((size_t)b << 18) + hw;
    float lsum = 0.f;
#pragma unroll
    for (int d = 0; d < D; ++d) {
        float qd = qv[d];
        op[(size_t)d << 12] = qd;                 // coalesced across w
        float diff = xv[d] - qd;
        lsum = fmaf(diff, diff, lsum);
    }

    // deterministic block reduction of the loss
#pragma unroll
    for (int off = 32; off > 0; off >>= 1)
        lsum += __shfl_down(lsum, off, 64);
    __shared__ float wsum[4];
    if ((threadIdx.x & 63) == 0) wsum[threadIdx.x >> 6] = lsum;
    __syncthreads();
    if (threadIdx.x == 0)
        partial[blockIdx.x] = (wsum[0] + wsum[1]) + (wsum[2] + wsum[3]);
}

__global__ __launch_bounds__(256) void vq_final(const float* __restrict__ partial,
                                                float* __restrict__ out) {
    int t = threadIdx.x;
    float s = partial[t] + partial[t + 256];
#pragma unroll
    for (int off = 32; off > 0; off >>= 1)
        s += __shfl_down(s, off, 64);
    __shared__ float wsum[4];
    if ((t & 63) == 0) wsum[t >> 6] = s;
    __syncthreads();
    if (t == 0)
        out[L_OFF] = ((wsum[0] + wsum[1]) + (wsum[2] + wsum[3])) * (1.f / 8388608.f);
}

extern "C" void kernel_launch(void* const* d_in, const int* in_sizes, int n_in,
                              void* d_out, int out_size, void* d_ws, size_t ws_size,
                              hipStream_t stream) {
    const float* x = (const float*)d_in[0];
    const float* E = (const float*)d_in[1];
    float* out = (float*)d_out;
    float* ws  = (float*)d_ws;

    hipLaunchKernelGGL(vq_prep,  dim3(2),   dim3(256), 0, stream, E, ws);
    hipLaunchKernelGGL(vq_main,  dim3(512), dim3(256), 0, stream, x, ws, out, ws + WS_PART);
    hipLaunchKernelGGL(vq_final, dim3(1),   dim3(256), 0, stream, ws + WS_PART, out);
}